// Round 1
// baseline (70.691 us; speedup 1.0000x reference)
//
#include <hip/hip_runtime.h>
#include <hip/hip_bf16.h>
#include <math.h>

#define K_COMP 64
#define LOG_2PI_D 1.837877066409345483560659472811
#define LOG2E_D   1.442695040888963407359924681002
#define LN2_F     0.69314718055994530942f

// ---------------------------------------------------------------------------
// Setup: one wave (64 threads), one thread per component.
// Produces 6 coefficients per k (scaled by log2(e)) such that
//   weighted[n,k]*log2(e) = A*x0^2 + B*x0*x1 + C*x1^2 + D*x0 + E*x1 + F
// ---------------------------------------------------------------------------
__global__ void gmm_setup(const float* __restrict__ means,
                          const float* __restrict__ chol_var,
                          const float* __restrict__ pi,
                          float* __restrict__ coef) {
    int k = threadIdx.x;  // 0..63

    // log_softmax(pi) across the wave (64 lanes)
    float p = pi[k];
    float mx = p;
    #pragma unroll
    for (int off = 32; off > 0; off >>= 1) mx = fmaxf(mx, __shfl_xor(mx, off, 64));
    double e = exp((double)p - (double)mx);
    double ssum = e;
    // sum-reduce in double via shuffle on hi/lo words is awkward; do float path
    float ef = (float)e;
    float sf = ef;
    #pragma unroll
    for (int off = 32; off > 0; off >>= 1) sf += __shfl_xor(sf, off, 64);
    double logpi = (double)p - ((double)mx + log((double)sf));

    // tril(chol_var) -> L ; cov = L L^T + eps I
    double v00 = (double)chol_var[k*4 + 0];
    double v10 = (double)chol_var[k*4 + 2];
    double v11 = (double)chol_var[k*4 + 3];
    const double eps = 1e-6;
    double cov00 = v00*v00 + eps;
    double cov01 = v00*v10;
    double cov11 = v10*v10 + v11*v11 + eps;

    // cholesky of cov: [[a,0],[b,c]]
    double a = sqrt(cov00);
    double b = cov01 / a;
    double c = sqrt(cov11 - b*b);
    double logdet = 2.0*(log(a) + log(c));

    // precision matrix P = cinv^T cinv, cinv = [[1/a,0],[-b/(ac),1/c]]
    double P00 = 1.0/(a*a) + (b*b)/(a*a*c*c);
    double P01 = -b/(a*c*c);
    double P11 = 1.0/(c*c);

    double m0 = (double)means[k*2 + 0];
    double m1 = (double)means[k*2 + 1];

    double constk = -0.5*(2.0*LOG_2PI_D + logdet) + logpi;

    // w = constk - 0.5*quad(x), expanded in x; scale everything by log2(e)
    coef[k*6 + 0] = (float)(-0.5*P00*LOG2E_D);                 // * x0^2
    coef[k*6 + 1] = (float)(-P01*LOG2E_D);                     // * x0*x1
    coef[k*6 + 2] = (float)(-0.5*P11*LOG2E_D);                 // * x1^2
    coef[k*6 + 3] = (float)((P00*m0 + P01*m1)*LOG2E_D);        // * x0
    coef[k*6 + 4] = (float)((P01*m0 + P11*m1)*LOG2E_D);        // * x1
    coef[k*6 + 5] = (float)((constk
                     - 0.5*(P00*m0*m0 + 2.0*P01*m0*m1 + P11*m1*m1))*LOG2E_D);
}

// ---------------------------------------------------------------------------
// Main: one point per thread. Two-pass logsumexp with w kept in VGPRs.
// ---------------------------------------------------------------------------
__global__ __launch_bounds__(256) void gmm_main(const float* __restrict__ x,
                                                const float* __restrict__ coef,
                                                float* __restrict__ out,
                                                int n) {
    int i = blockIdx.x * 256 + threadIdx.x;
    if (i >= n) return;

    float2 xv = reinterpret_cast<const float2*>(x)[i];
    float x0 = xv.x, x1 = xv.y;
    float x00 = x0*x0, x01 = x0*x1, x11 = x1*x1;

    float w[K_COMP];
    float m = -INFINITY;
    #pragma unroll
    for (int k = 0; k < K_COMP; ++k) {
        float t = coef[k*6 + 5];                // uniform -> s_load
        t = fmaf(coef[k*6 + 0], x00, t);
        t = fmaf(coef[k*6 + 1], x01, t);
        t = fmaf(coef[k*6 + 2], x11, t);
        t = fmaf(coef[k*6 + 3], x0,  t);
        t = fmaf(coef[k*6 + 4], x1,  t);
        w[k] = t;
        m = fmaxf(m, t);
    }

    float s0 = 0.f, s1 = 0.f, s2 = 0.f, s3 = 0.f;
    #pragma unroll
    for (int k = 0; k < K_COMP; k += 4) {
        s0 += __builtin_amdgcn_exp2f(w[k]     - m);
        s1 += __builtin_amdgcn_exp2f(w[k + 1] - m);
        s2 += __builtin_amdgcn_exp2f(w[k + 2] - m);
        s3 += __builtin_amdgcn_exp2f(w[k + 3] - m);
    }
    float s = (s0 + s1) + (s2 + s3);

    out[i] = LN2_F * (m + __builtin_amdgcn_logf(s));
}

extern "C" void kernel_launch(void* const* d_in, const int* in_sizes, int n_in,
                              void* d_out, int out_size, void* d_ws, size_t ws_size,
                              hipStream_t stream) {
    const float* x        = (const float*)d_in[0];
    const float* means    = (const float*)d_in[1];
    const float* chol_var = (const float*)d_in[2];
    const float* pi       = (const float*)d_in[3];
    float* out  = (float*)d_out;
    float* coef = (float*)d_ws;   // 64*6 floats = 1.5 KB

    int n = in_sizes[0] / 2;      // N points (D=2)

    gmm_setup<<<1, 64, 0, stream>>>(means, chol_var, pi, coef);
    gmm_main<<<(n + 255) / 256, 256, 0, stream>>>(x, coef, out, n);
}

// Round 2
// 69.502 us; speedup vs baseline: 1.0171x; 1.0171x over previous
//
#include <hip/hip_runtime.h>
#include <hip/hip_bf16.h>
#include <math.h>
#include <stdint.h>

#define K_COMP 64
#define LOG_2PI_D 1.837877066409345483560659472811
#define LOG2E_D   1.442695040888963407359924681002
#define LN2_F     0.69314718055994530942f

// ---------------------------------------------------------------------------
// Setup: one wave (64 threads), one thread per component.
// Produces 6 coefficients per k (scaled by log2(e)) such that
//   weighted[n,k]*log2(e) = A*x0^2 + B*x0*x1 + C*x1^2 + D*x0 + E*x1 + F
// Double for algebra (HW fp64 ops, cheap), float for transcendentals.
// ---------------------------------------------------------------------------
__global__ void gmm_setup(const float* __restrict__ means,
                          const float* __restrict__ chol_var,
                          const float* __restrict__ pi,
                          float* __restrict__ coef) {
    int k = threadIdx.x;  // 0..63

    // log_softmax(pi) across the wave (64 lanes)
    float p = pi[k];
    float mx = p;
    #pragma unroll
    for (int off = 32; off > 0; off >>= 1) mx = fmaxf(mx, __shfl_xor(mx, off, 64));
    float ef = __expf(p - mx);
    float sf = ef;
    #pragma unroll
    for (int off = 32; off > 0; off >>= 1) sf += __shfl_xor(sf, off, 64);
    double logpi = (double)p - (double)mx - (double)__logf(sf);

    // tril(chol_var) -> L ; cov = L L^T + eps I
    double v00 = (double)chol_var[k*4 + 0];
    double v10 = (double)chol_var[k*4 + 2];
    double v11 = (double)chol_var[k*4 + 3];
    const double eps = 1e-6;
    double cov00 = v00*v00 + eps;
    double cov01 = v00*v10;
    double cov11 = v10*v10 + v11*v11 + eps;

    // cholesky of cov: [[a,0],[b,c]]
    double a = sqrt(cov00);
    double b = cov01 / a;
    double c2 = cov11 - b*b;          // c^2
    double c = sqrt(c2);
    // logdet = 2*(log a + log c) = log(a^2 * c^2)
    double logdet = (double)__logf((float)(cov00 * c2));

    // precision matrix P = cinv^T cinv, cinv = [[1/a,0],[-b/(ac),1/c]]
    double P00 = 1.0/cov00 + (b*b)/(cov00*c2);
    double P01 = -b/(a*c2);
    double P11 = 1.0/c2;

    double m0 = (double)means[k*2 + 0];
    double m1 = (double)means[k*2 + 1];

    double constk = -0.5*(2.0*LOG_2PI_D + logdet) + logpi;

    // w = constk - 0.5*quad(x), expanded in x; scale everything by log2(e)
    coef[k*6 + 0] = (float)(-0.5*P00*LOG2E_D);                 // * x0^2
    coef[k*6 + 1] = (float)(-P01*LOG2E_D);                     // * x0*x1
    coef[k*6 + 2] = (float)(-0.5*P11*LOG2E_D);                 // * x1^2
    coef[k*6 + 3] = (float)((P00*m0 + P01*m1)*LOG2E_D);        // * x0
    coef[k*6 + 4] = (float)((P01*m0 + P11*m1)*LOG2E_D);        // * x1
    coef[k*6 + 5] = (float)((constk
                     - 0.5*(P00*m0*m0 + 2.0*P01*m0*m1 + P11*m1*m1))*LOG2E_D);
}

// ---------------------------------------------------------------------------
// Main: one point per thread. Two-pass logsumexp with w kept in VGPRs.
// Coefficients read through constant address space -> s_load (scalar pipe),
// not per-lane global_load. (composable_kernel's
// cast_pointer_to_constant_address_space trick.)
// ---------------------------------------------------------------------------
typedef const float __attribute__((address_space(4))) cfloat;

__global__ __launch_bounds__(256) void gmm_main(const float* __restrict__ x,
                                                const float* __restrict__ coef,
                                                float* __restrict__ out,
                                                int n) {
    int i = blockIdx.x * 256 + threadIdx.x;
    if (i >= n) return;

    cfloat* cc = (cfloat*)(uintptr_t)coef;

    float2 xv = reinterpret_cast<const float2*>(x)[i];
    float x0 = xv.x, x1 = xv.y;
    float x00 = x0*x0, x01 = x0*x1, x11 = x1*x1;

    float w[K_COMP];
    float m = -INFINITY;
    #pragma unroll
    for (int k = 0; k < K_COMP; ++k) {
        float t = cc[k*6 + 5];                  // s_load, SGPR operand
        t = fmaf(cc[k*6 + 0], x00, t);
        t = fmaf(cc[k*6 + 1], x01, t);
        t = fmaf(cc[k*6 + 2], x11, t);
        t = fmaf(cc[k*6 + 3], x0,  t);
        t = fmaf(cc[k*6 + 4], x1,  t);
        w[k] = t;
        m = fmaxf(m, t);
    }

    float s0 = 0.f, s1 = 0.f, s2 = 0.f, s3 = 0.f;
    #pragma unroll
    for (int k = 0; k < K_COMP; k += 4) {
        s0 += __builtin_amdgcn_exp2f(w[k]     - m);
        s1 += __builtin_amdgcn_exp2f(w[k + 1] - m);
        s2 += __builtin_amdgcn_exp2f(w[k + 2] - m);
        s3 += __builtin_amdgcn_exp2f(w[k + 3] - m);
    }
    float s = (s0 + s1) + (s2 + s3);

    out[i] = LN2_F * (m + __builtin_amdgcn_logf(s));
}

extern "C" void kernel_launch(void* const* d_in, const int* in_sizes, int n_in,
                              void* d_out, int out_size, void* d_ws, size_t ws_size,
                              hipStream_t stream) {
    const float* x        = (const float*)d_in[0];
    const float* means    = (const float*)d_in[1];
    const float* chol_var = (const float*)d_in[2];
    const float* pi       = (const float*)d_in[3];
    float* out  = (float*)d_out;
    float* coef = (float*)d_ws;   // 64*6 floats = 1.5 KB

    int n = in_sizes[0] / 2;      // N points (D=2)

    gmm_setup<<<1, 64, 0, stream>>>(means, chol_var, pi, coef);
    gmm_main<<<(n + 255) / 256, 256, 0, stream>>>(x, coef, out, n);
}